// Round 11
// baseline (185.428 us; speedup 1.0000x reference)
//
#include <hip/hip_runtime.h>

// out[n,k,y,x] = sum_c grid[n,k,c,y/16,x/16] * guidemap[n,c,y,x]
// N=2, K=C=32, H=W=1024, 64x64 tiles of 16x16 px.
//
// R11: maximum memory-level-parallelism discriminator.
//  - ALL 32 guide channel loads issued up-front per thread (32 x v2f =
//    16 KB in flight per wave, 4x the ring-4 designs) -- tests whether
//    the 3.4 TB/s-effective invariant of R3/R9/R10 is a latency x
//    concurrency equilibrium rather than a fabric ceiling.
//  - Thread = 2 px x 16 k: acc[16] v2f (32 VGPR) + guide (64 VGPR)
//    ~ 112 VGPR total -> 4 waves/SIMD still possible.
//  - WG = 256 thr = ONE tile: waves = (px-half) x (k-half). 4 KB matrix
//    staged once via global_load_lds; wave-uniform ds_read_b128
//    broadcast; single barrier; plain stores (L2 merges half-lines).
//  - XCD-contiguous tile assignment as before.

namespace {
constexpr int K = 32, C = 32;
constexpr int W = 1024;
constexpr int HW = 1024 * 1024;
constexpr size_t GRDN = (size_t)K * C * 64 * 64;  // floats per image
}

typedef float v2f __attribute__((ext_vector_type(2)));
typedef float v4f __attribute__((ext_vector_type(4)));

__device__ __forceinline__ void gl_lds4(const float* src, float* dst) {
    __builtin_amdgcn_global_load_lds(
        (const __attribute__((address_space(1))) void*)src,
        (__attribute__((address_space(3))) void*)dst, 4, 0, 0);
}

__global__ __launch_bounds__(256, 4) void gridup_kernel(
    const float* __restrict__ grd,   // [N][K][C][64][64]
    const float* __restrict__ gm,    // [N][C][1024][1024]
    float* __restrict__ out)         // [N][K][1024][1024]
{
    __shared__ float sM[C][K];       // one tile's matrix, 4 KB

    const int b  = blockIdx.x;                  // 0..8191
    const int gt = (b & 7) * 1024 + (b >> 3);   // XCD-contiguous tiles
    const int t  = threadIdx.x;

    const int n  = gt >> 12;
    const int rr = gt & 4095;
    const int by = rr >> 6;
    const int bx = rr & 63;

    // ---- stage matrix: e = c*32 + k, 1024 dword gathers (L2-deduped)
    #pragma unroll
    for (int i = 0; i < 4; ++i) {
        const int e = i * 256 + t;   // 0..1023
        const int c = e >> 5;
        const int k = e & 31;
        gl_lds4(grd + (size_t)n * GRDN + (size_t)(k * 32 + c) * 4096 +
                    by * 64 + bx,
                &sM[0][0] + e);
    }
    __syncthreads();   // only barrier in the kernel

    const int w  = t >> 6;           // wave 0..3
    const int ph = w & 1;            // px half: 0 -> px 0..127, 1 -> 128..255
    const int kh = w >> 1;           // k half:  0 -> k 0..15,  1 -> 16..31
    const int l  = t & 63;

    const int p   = ph * 128 + l * 2;    // even px within tile
    const int row = p >> 4;
    const int col = p & 15;
    const size_t pix = (size_t)(by * 16 + row) * W + bx * 16 + col;
    const float* gb = gm + (size_t)n * C * HW + pix;
    float*       ob = out + ((size_t)n * K + kh * 16) * HW + pix;
    const float* Mb = &sM[0][kh * 16];

    // ---- issue ALL 32 guide loads up-front: 16 KB in flight per wave
    v2f g[32];
    #pragma unroll
    for (int c = 0; c < C; ++c)
        g[c] = *reinterpret_cast<const v2f*>(gb + (size_t)c * HW);

    v2f acc[16];
    #pragma unroll
    for (int k = 0; k < 16; ++k) acc[k] = (v2f)0.f;

    #pragma unroll
    for (int c = 0; c < C; ++c) {
        const v2f u = g[c];
        #pragma unroll
        for (int kq = 0; kq < 4; ++kq) {
            // wave-uniform 16B LDS read: broadcast, conflict-free
            const v4f m = *reinterpret_cast<const v4f*>(Mb + c * K + kq * 4);
            acc[kq * 4 + 0] += m.x * u;
            acc[kq * 4 + 1] += m.y * u;
            acc[kq * 4 + 2] += m.z * u;
            acc[kq * 4 + 3] += m.w * u;
        }
    }

    // ---- plain v2f stores: L2 merges adjacent half-lines
    #pragma unroll
    for (int k = 0; k < 16; ++k) {
        *reinterpret_cast<v2f*>(ob + (size_t)k * HW) = acc[k];
    }
}

extern "C" void kernel_launch(void* const* d_in, const int* in_sizes, int n_in,
                              void* d_out, int out_size, void* d_ws, size_t ws_size,
                              hipStream_t stream) {
    const float* grd = (const float*)d_in[0];   // grid:     2*32*32*64*64
    const float* gm  = (const float*)d_in[1];   // guidemap: 2*32*1024*1024
    float* out = (float*)d_out;                 // 2*32*1024*1024 fp32

    gridup_kernel<<<8192, 256, 0, stream>>>(grd, gm, out);
}